// Round 8
// baseline (180.162 us; speedup 1.0000x reference)
//
#include <hip/hip_runtime.h>

#define D 32          // MOTIF_DIM
#define H 64          // HIDDEN

typedef __attribute__((ext_vector_type(8))) short bf16x8;
typedef __attribute__((ext_vector_type(4))) float f32x4;

union AB { uint4 u; bf16x8 v; };

__device__ __forceinline__ short f2bf_s(float f) {   // round-to-nearest-even
  unsigned u = __float_as_uint(f);
  u += 0x7fffu + ((u >> 16) & 1u);
  return (short)(u >> 16);
}

// pack two f32 (lo,hi) into one dword of bf16 [lo | hi<<16], round-to-zero.
__device__ __forceinline__ unsigned pack_bf2(float lo, float hi) {
  return __builtin_amdgcn_perm(__float_as_uint(hi), __float_as_uint(lo), 0x07060302u);
}

// DPP 16-lane row reduction (rows of 16 = our q-groups). After 4 steps every
// lane in the row holds the row sum. All VALU, no DS, ~4cyc dependent latency.
template <int CTRL>
__device__ __forceinline__ float dppadd(float x) {
  int s = __builtin_amdgcn_update_dpp(0, __float_as_int(x), CTRL, 0xF, 0xF, true);
  return x + __int_as_float(s);
}
__device__ __forceinline__ float row16_sum(float x) {
  x = dppadd<0xB1>(x);    // quad_perm [1,0,3,2]  : lane ^ 1
  x = dppadd<0x4E>(x);    // quad_perm [2,3,0,1]  : lane ^ 2
  x = dppadd<0x141>(x);   // row_half_mirror      : combines quads within 8
  x = dppadd<0x140>(x);   // row_mirror           : combines the two halves
  return x;
}

// ---------------------------------------------------------------------------
// Fused prep: blocks [0, nPack) convert x fp32 -> bf16 rows (RNE);
// remaining blocks build the W1 B-fragment table (16 frags x 64 lanes x 8 bf16).
// Frag f = t*4+s: lane l elem j = W1[s*32+(l>>4)*8+j][t*16+(l&15)].
// ---------------------------------------------------------------------------
__global__ __launch_bounds__(256) void prep(
    const float* __restrict__ x, const float* __restrict__ W1,
    short* __restrict__ xbf, short* __restrict__ btab, int n4, int nPack) {
  int b = blockIdx.x;
  if (b < nPack) {
    int i = b * 256 + threadIdx.x;
    if (i < n4) {
      float4 v = ((const float4*)x)[i];
      short4 o;
      o.x = f2bf_s(v.x); o.y = f2bf_s(v.y); o.z = f2bf_s(v.z); o.w = f2bf_s(v.w);
      ((short4*)xbf)[i] = o;
    }
  } else {
    int id = (b - nPack) * 256 + threadIdx.x;      // 0..8191
    if (id < 16 * 64 * 8) {
      int j = id & 7;
      int l = (id >> 3) & 63;
      int f = id >> 9;
      int s = f & 3, t = f >> 2;
      int k = s * 32 + (l >> 4) * 8 + j;
      int n = t * 16 + (l & 15);
      btab[id] = f2bf_s(W1[k * H + n]);
    }
  }
}

// ---------------------------------------------------------------------------
// Compute one 16-edge tile from gathered A-operands: c,p frags in-lane,
// 16 MFMA with bias as C-input, fused layer-2, DPP row-reduce, sigmoid, write.
// ---------------------------------------------------------------------------
__device__ __forceinline__ void compute_tile(
    uint4 muU, uint4 mvU, const bf16x8* __restrict__ B,
    const float* __restrict__ b1v, const float* __restrict__ w2v, float bias2,
    int tile, int q, int m, int nE, float* __restrict__ out) {
  AB mu, mv, ac, ap;
  mu.u = muU; mv.u = mvU;
#pragma unroll
  for (int k = 0; k < 4; ++k) {
    unsigned a = (&mu.u.x)[k], b = (&mv.u.x)[k];
    float alo = __uint_as_float(a << 16);
    float ahi = __uint_as_float(a & 0xffff0000u);
    float blo = __uint_as_float(b << 16);
    float bhi = __uint_as_float(b & 0xffff0000u);
    float dlo = alo - blo, dhi = ahi - bhi;
    (&ac.u.x)[k] = pack_bf2(dlo, dhi) & 0x7fff7fffu;   // packed abs
    (&ap.u.x)[k] = pack_bf2(alo * blo, ahi * bhi);
  }

  float part[4];
#pragma unroll
  for (int t = 0; t < 4; ++t) {
    float bv = b1v[t];
    f32x4 acc = (f32x4){bv, bv, bv, bv};               // bias as MFMA C-input
    acc = __builtin_amdgcn_mfma_f32_16x16x32_bf16(mu.v, B[t * 4 + 0], acc, 0, 0, 0);
    acc = __builtin_amdgcn_mfma_f32_16x16x32_bf16(mv.v, B[t * 4 + 1], acc, 0, 0, 0);
    acc = __builtin_amdgcn_mfma_f32_16x16x32_bf16(ac.v, B[t * 4 + 2], acc, 0, 0, 0);
    acc = __builtin_amdgcn_mfma_f32_16x16x32_bf16(ap.v, B[t * 4 + 3], acc, 0, 0, 0);
#pragma unroll
    for (int r = 0; r < 4; ++r) {
      float h = fmaxf(acc[r], 0.f);
      part[r] = (t == 0) ? h * w2v[0] : fmaf(h, w2v[t], part[r]);
    }
  }

  // sum over hidden (the 16 lanes of this row) — all-VALU DPP butterflies
#pragma unroll
  for (int r = 0; r < 4; ++r) part[r] = row16_sum(part[r]);

  if (m < 4) {
    int ew = tile * 16 + q * 4 + m;    // overflow tiles -> ew >= nE -> no write
    if (ew < nE) {
      float z = (m == 0 ? part[0] : m == 1 ? part[1] : m == 2 ? part[2] : part[3])
                + bias2;
      out[ew] = 1.f / (1.f + __expf(-z));   // sigmoid in (0,1): clip is no-op
    }
  }
}

// ---------------------------------------------------------------------------
// Main: each wave handles PAIRS of consecutive tiles (32 consecutive edges),
// grid-stride over pairs. Pipeline: idx(p+2nW) and gathers(p+nW) in flight
// while computing p. Idx load is one fully-coalesced dword per lane
// (lane>>5 = src/dst, lane&31 = edge-in-pair), distributed via 4 shfl.
// __launch_bounds__(256,4): force allocator to fit 4 waves/SIMD.
// ---------------------------------------------------------------------------
__global__ __launch_bounds__(256, 4) void edge_mfma(
    const short* __restrict__ xbf, const short* __restrict__ btab,
    const int* __restrict__ ei,
    const float* __restrict__ b1, const float* __restrict__ W2,
    const float* __restrict__ b2, float* __restrict__ out,
    int nE, int nPairs) {
  int lane = threadIdx.x & 63;
  int wid  = (blockIdx.x * 256 + threadIdx.x) >> 6;
  int nW   = (gridDim.x * 256) >> 6;
  int m = lane & 15;        // edge-in-tile (A rows) / hidden-in-tile (C cols)
  int q = lane >> 4;        // quad
  if (wid >= nPairs) return;

  bf16x8 B[16];
#pragma unroll
  for (int f = 0; f < 16; ++f)
    B[f] = *(const bf16x8*)(btab + (f * 64 + lane) * 8);

  float b1v[4], w2v[4];
#pragma unroll
  for (int t = 0; t < 4; ++t) {
    b1v[t] = b1[t * 16 + m];
    w2v[t] = W2[t * 16 + m];
  }
  float bias2 = b2[0];

  const uint4* xb = (const uint4*)xbf;   // node row = 4 uint4; lane reads row*4+q
  int eLim = nE - 1;
  int pLim = nPairs - 1;
  int selOff = (lane >> 5) ? nE : 0;     // src half / dst half
  int eoff = lane & 31;

  // ---- prologue ----
  int p = wid;
  int idxNxt;
  uint4 amu0, amv0, amu1, amv1;
  {
    int e = p * 32 + eoff; e = e < nE ? e : eLim;
    int idxCur = ei[selOff + e];
    int sn0 = __shfl(idxCur, m);
    int sn1 = __shfl(idxCur, 16 + m);
    int dn0 = __shfl(idxCur, 32 + m);
    int dn1 = __shfl(idxCur, 48 + m);
    amu0 = xb[sn0 * 4 + q]; amv0 = xb[dn0 * 4 + q];
    amu1 = xb[sn1 * 4 + q]; amv1 = xb[dn1 * 4 + q];
    int p1 = p + nW; p1 = p1 < nPairs ? p1 : pLim;
    int e1 = p1 * 32 + eoff; e1 = e1 < nE ? e1 : eLim;
    idxNxt = ei[selOff + e1];
  }

  while (p < nPairs) {
    int pn = p + nW;
    // distribute next pair's ids, issue its gathers
    int sn0 = __shfl(idxNxt, m);
    int sn1 = __shfl(idxNxt, 16 + m);
    int dn0 = __shfl(idxNxt, 32 + m);
    int dn1 = __shfl(idxNxt, 48 + m);
    uint4 bmu0 = xb[sn0 * 4 + q], bmv0 = xb[dn0 * 4 + q];
    uint4 bmu1 = xb[sn1 * 4 + q], bmv1 = xb[dn1 * 4 + q];
    // issue idx load for p + 2nW (consumed next iteration)
    {
      int p2 = pn + nW; p2 = p2 < nPairs ? p2 : pLim;
      int e2 = p2 * 32 + eoff; e2 = e2 < nE ? e2 : eLim;
      idxNxt = ei[selOff + e2];
    }
    // compute current pair
    compute_tile(amu0, amv0, B, b1v, w2v, bias2, p * 2,     q, m, nE, out);
    compute_tile(amu1, amv1, B, b1v, w2v, bias2, p * 2 + 1, q, m, nE, out);

    amu0 = bmu0; amv0 = bmv0; amu1 = bmu1; amv1 = bmv1;
    p = pn;
  }
}

// ---------------------------------------------------------------------------
// Fallback (ws too small): all-fp32 per edge, no workspace needed.
// ---------------------------------------------------------------------------
__global__ __launch_bounds__(256) void edge_full(
    const float* __restrict__ x, const int* __restrict__ ei,
    const float* __restrict__ W1, const float* __restrict__ b1,
    const float* __restrict__ W2, const float* __restrict__ b2,
    float* __restrict__ out, int nE) {
  int e = blockIdx.x * 256 + threadIdx.x;
  if (e >= nE) return;
  int s = ei[e];
  int d = ei[e + nE];
  const float4* mu4 = (const float4*)(x + (size_t)s * D);
  const float4* mv4 = (const float4*)(x + (size_t)d * D);
  float mu[D], mv[D], c[D], p[D];
#pragma unroll
  for (int qq = 0; qq < D / 4; ++qq) {
    float4 a = mu4[qq];
    float4 b = mv4[qq];
    mu[4*qq+0] = a.x; mv[4*qq+0] = b.x; c[4*qq+0] = fabsf(a.x-b.x); p[4*qq+0] = a.x*b.x;
    mu[4*qq+1] = a.y; mv[4*qq+1] = b.y; c[4*qq+1] = fabsf(a.y-b.y); p[4*qq+1] = a.y*b.y;
    mu[4*qq+2] = a.z; mv[4*qq+2] = b.z; c[4*qq+2] = fabsf(a.z-b.z); p[4*qq+2] = a.z*b.z;
    mu[4*qq+3] = a.w; mv[4*qq+3] = b.w; c[4*qq+3] = fabsf(a.w-b.w); p[4*qq+3] = a.w*b.w;
  }
  float z = b2[0];
  for (int j = 0; j < H; ++j) {
    float a = b1[j];
#pragma unroll
    for (int k = 0; k < D; ++k) {
      a = fmaf(mu[k], W1[k * H + j], a);
      a = fmaf(mv[k], W1[(D + k) * H + j], a);
      a = fmaf(c[k],  W1[(2 * D + k) * H + j], a);
      a = fmaf(p[k],  W1[(3 * D + k) * H + j], a);
    }
    a = fmaxf(a, 0.f);
    z = fmaf(a, W2[j], z);
  }
  float g = 1.f / (1.f + __expf(-z));
  out[e] = fminf(fmaxf(g, 0.f), 1.f);
}

extern "C" void kernel_launch(void* const* d_in, const int* in_sizes, int n_in,
                              void* d_out, int out_size, void* d_ws, size_t ws_size,
                              hipStream_t stream) {
  const float* x  = (const float*)d_in[0];
  const int*   ei = (const int*)d_in[1];
  const float* W1 = (const float*)d_in[2];
  const float* b1 = (const float*)d_in[3];
  const float* W2 = (const float*)d_in[4];
  const float* b2 = (const float*)d_in[5];
  float* out = (float*)d_out;

  int nN = in_sizes[0] / D;      // 100000
  int nE = in_sizes[1] / 2;      // 1600000

  size_t xbf_shorts = (size_t)nN * D;                     // 6.4 MB
  size_t need = (xbf_shorts + 16 * 64 * 8) * sizeof(short);
  if (ws_size >= need) {
    short* xbf  = (short*)d_ws;
    short* btab = xbf + xbf_shorts;
    int n4 = nN * D / 4;
    int nPack = (n4 + 255) / 256;
    int nBt = (16 * 64 * 8 + 255) / 256;
    prep<<<nPack + nBt, 256, 0, stream>>>(x, W1, xbf, btab, n4, nPack);
    int nTiles = (nE + 15) / 16;
    int nPairs = (nTiles + 1) / 2;
    edge_mfma<<<2048, 256, 0, stream>>>(xbf, btab, ei, b1, W2, b2, out, nE, nPairs);
  } else {
    edge_full<<<(nE + 255) / 256, 256, 0, stream>>>(x, ei, W1, b1, W2, b2, out, nE);
  }
}

// Round 9
// 124.206 us; speedup vs baseline: 1.4505x; 1.4505x over previous
//
#include <hip/hip_runtime.h>

#define D 32          // MOTIF_DIM
#define H 64          // HIDDEN

typedef __attribute__((ext_vector_type(8))) short bf16x8;
typedef __attribute__((ext_vector_type(4))) float f32x4;

union AB { uint4 u; bf16x8 v; };

__device__ __forceinline__ short f2bf_s(float f) {   // round-to-nearest-even
  unsigned u = __float_as_uint(f);
  u += 0x7fffu + ((u >> 16) & 1u);
  return (short)(u >> 16);
}

// pack two f32 (lo,hi) into one dword of bf16 [lo | hi<<16], round-to-zero.
__device__ __forceinline__ unsigned pack_bf2(float lo, float hi) {
  return __builtin_amdgcn_perm(__float_as_uint(hi), __float_as_uint(lo), 0x07060302u);
}

// DPP 16-lane row reduction (rows of 16 = our q-groups). All VALU, no DS.
template <int CTRL>
__device__ __forceinline__ float dppadd(float x) {
  int s = __builtin_amdgcn_update_dpp(0, __float_as_int(x), CTRL, 0xF, 0xF, true);
  return x + __int_as_float(s);
}
__device__ __forceinline__ float row16_sum(float x) {
  x = dppadd<0xB1>(x);    // quad_perm [1,0,3,2]  : lane ^ 1
  x = dppadd<0x4E>(x);    // quad_perm [2,3,0,1]  : lane ^ 2
  x = dppadd<0x141>(x);   // row_half_mirror
  x = dppadd<0x140>(x);   // row_mirror
  return x;
}

// ---------------------------------------------------------------------------
// Fused prep: blocks [0, nPack) convert x fp32 -> bf16 rows (RNE);
// remaining blocks build the W1 B-fragment table (16 frags x 64 lanes x 8 bf16).
// Frag f = t*4+s: lane l elem j = W1[s*32+(l>>4)*8+j][t*16+(l&15)].
// ---------------------------------------------------------------------------
__global__ __launch_bounds__(256) void prep(
    const float* __restrict__ x, const float* __restrict__ W1,
    short* __restrict__ xbf, short* __restrict__ btab, int n4, int nPack) {
  int b = blockIdx.x;
  if (b < nPack) {
    int i = b * 256 + threadIdx.x;
    if (i < n4) {
      float4 v = ((const float4*)x)[i];
      short4 o;
      o.x = f2bf_s(v.x); o.y = f2bf_s(v.y); o.z = f2bf_s(v.z); o.w = f2bf_s(v.w);
      ((short4*)xbf)[i] = o;
    }
  } else {
    int id = (b - nPack) * 256 + threadIdx.x;      // 0..8191
    if (id < 16 * 64 * 8) {
      int j = id & 7;
      int l = (id >> 3) & 63;
      int f = id >> 9;
      int s = f & 3, t = f >> 2;
      int k = s * 32 + (l >> 4) * 8 + j;
      int n = t * 16 + (l & 15);
      btab[id] = f2bf_s(W1[k * H + n]);
    }
  }
}

// ---------------------------------------------------------------------------
// Compute one 16-edge tile. B-fragments are read from LDS (bl = base + lane*16B,
// frag f at immediate offset f*1KB) right before each MFMA.
// ---------------------------------------------------------------------------
__device__ __forceinline__ void compute_tile(
    uint4 muU, uint4 mvU, const short* __restrict__ bl,
    const float* __restrict__ b1v, const float* __restrict__ w2v, float bias2,
    int tile, int q, int m, int nE, float* __restrict__ out) {
  AB mu, mv, ac, ap;
  mu.u = muU; mv.u = mvU;
#pragma unroll
  for (int k = 0; k < 4; ++k) {
    unsigned a = (&mu.u.x)[k], b = (&mv.u.x)[k];
    float alo = __uint_as_float(a << 16);
    float ahi = __uint_as_float(a & 0xffff0000u);
    float blo = __uint_as_float(b << 16);
    float bhi = __uint_as_float(b & 0xffff0000u);
    float dlo = alo - blo, dhi = ahi - bhi;
    (&ac.u.x)[k] = pack_bf2(dlo, dhi) & 0x7fff7fffu;   // packed abs
    (&ap.u.x)[k] = pack_bf2(alo * blo, ahi * bhi);
  }

  float part[4];
#pragma unroll
  for (int t = 0; t < 4; ++t) {
    float bv = b1v[t];
    f32x4 acc = (f32x4){bv, bv, bv, bv};               // bias as MFMA C-input
    acc = __builtin_amdgcn_mfma_f32_16x16x32_bf16(
        mu.v, *(const bf16x8*)(bl + (t * 4 + 0) * 512), acc, 0, 0, 0);
    acc = __builtin_amdgcn_mfma_f32_16x16x32_bf16(
        mv.v, *(const bf16x8*)(bl + (t * 4 + 1) * 512), acc, 0, 0, 0);
    acc = __builtin_amdgcn_mfma_f32_16x16x32_bf16(
        ac.v, *(const bf16x8*)(bl + (t * 4 + 2) * 512), acc, 0, 0, 0);
    acc = __builtin_amdgcn_mfma_f32_16x16x32_bf16(
        ap.v, *(const bf16x8*)(bl + (t * 4 + 3) * 512), acc, 0, 0, 0);
#pragma unroll
    for (int r = 0; r < 4; ++r) {
      float h = fmaxf(acc[r], 0.f);
      part[r] = (t == 0) ? h * w2v[0] : fmaf(h, w2v[t], part[r]);
    }
  }

#pragma unroll
  for (int r = 0; r < 4; ++r) part[r] = row16_sum(part[r]);

  if (m < 4) {
    int ew = tile * 16 + q * 4 + m;    // overflow tiles -> ew >= nE -> no write
    if (ew < nE) {
      float z = (m == 0 ? part[0] : m == 1 ? part[1] : m == 2 ? part[2] : part[3])
                + bias2;
      out[ew] = 1.f / (1.f + __expf(-z));   // sigmoid in (0,1): clip is no-op
    }
  }
}

// ---------------------------------------------------------------------------
// Main: pairs of consecutive 16-edge tiles per wave, grid-stride; coalesced
// idx load + shfl distribute; idx/gather prefetch pipeline. B-fragment table
// staged in LDS (16 KB) — frees ~64 regs/wave so many waves stay resident.
// An empty asm opacifies the LDS offset each iteration to stop LICM from
// hoisting the 16 B-fragment loads back into registers.
// ---------------------------------------------------------------------------
__global__ __launch_bounds__(256) void edge_mfma(
    const short* __restrict__ xbf, const short* __restrict__ btab,
    const int* __restrict__ ei,
    const float* __restrict__ b1, const float* __restrict__ W2,
    const float* __restrict__ b2, float* __restrict__ out,
    int nE, int nPairs) {
  __shared__ short lds_b[16 * 64 * 8];   // 16 KB

  // stage B table: 1024 uint4, 256 threads x 4
  {
    const uint4* src = (const uint4*)btab;
    uint4* dst = (uint4*)lds_b;
#pragma unroll
    for (int i = 0; i < 4; ++i)
      dst[threadIdx.x + i * 256] = src[threadIdx.x + i * 256];
  }
  __syncthreads();

  int lane = threadIdx.x & 63;
  int wid  = (blockIdx.x * 256 + threadIdx.x) >> 6;
  int nW   = (gridDim.x * 256) >> 6;
  int m = lane & 15;        // edge-in-tile (A rows) / hidden-in-tile (C cols)
  int q = lane >> 4;        // quad
  if (wid >= nPairs) return;

  float b1v[4], w2v[4];
#pragma unroll
  for (int t = 0; t < 4; ++t) {
    b1v[t] = b1[t * 16 + m];
    w2v[t] = W2[t * 16 + m];
  }
  float bias2 = b2[0];

  const uint4* xb = (const uint4*)xbf;   // node row = 4 uint4; lane reads row*4+q
  int eLim = nE - 1;
  int pLim = nPairs - 1;
  int selOff = (lane >> 5) ? nE : 0;     // src half / dst half
  int eoff = lane & 31;

  // ---- prologue ----
  int p = wid;
  int idxNxt;
  uint4 amu0, amv0, amu1, amv1;
  {
    int e = p * 32 + eoff; e = e < nE ? e : eLim;
    int idxCur = ei[selOff + e];
    int sn0 = __shfl(idxCur, m);
    int sn1 = __shfl(idxCur, 16 + m);
    int dn0 = __shfl(idxCur, 32 + m);
    int dn1 = __shfl(idxCur, 48 + m);
    amu0 = xb[sn0 * 4 + q]; amv0 = xb[dn0 * 4 + q];
    amu1 = xb[sn1 * 4 + q]; amv1 = xb[dn1 * 4 + q];
    int p1 = p + nW; p1 = p1 < nPairs ? p1 : pLim;
    int e1 = p1 * 32 + eoff; e1 = e1 < nE ? e1 : eLim;
    idxNxt = ei[selOff + e1];
  }

  while (p < nPairs) {
    int pn = p + nW;
    // distribute next pair's ids, issue its gathers
    int sn0 = __shfl(idxNxt, m);
    int sn1 = __shfl(idxNxt, 16 + m);
    int dn0 = __shfl(idxNxt, 32 + m);
    int dn1 = __shfl(idxNxt, 48 + m);
    uint4 bmu0 = xb[sn0 * 4 + q], bmv0 = xb[dn0 * 4 + q];
    uint4 bmu1 = xb[sn1 * 4 + q], bmv1 = xb[dn1 * 4 + q];
    // issue idx load for p + 2nW (consumed next iteration)
    {
      int p2 = pn + nW; p2 = p2 < nPairs ? p2 : pLim;
      int e2 = p2 * 32 + eoff; e2 = e2 < nE ? e2 : eLim;
      idxNxt = ei[selOff + e2];
    }

    // opaque LDS base offset: stops LICM hoisting the B-frag LDS loads
    int bofs = lane * 8;
    asm volatile("" : "+v"(bofs));
    const short* bl = lds_b + bofs;

    // compute current pair
    compute_tile(amu0, amv0, bl, b1v, w2v, bias2, p * 2,     q, m, nE, out);
    compute_tile(amu1, amv1, bl, b1v, w2v, bias2, p * 2 + 1, q, m, nE, out);

    amu0 = bmu0; amv0 = bmv0; amu1 = bmu1; amv1 = bmv1;
    p = pn;
  }
}

// ---------------------------------------------------------------------------
// Fallback (ws too small): all-fp32 per edge, no workspace needed.
// ---------------------------------------------------------------------------
__global__ __launch_bounds__(256) void edge_full(
    const float* __restrict__ x, const int* __restrict__ ei,
    const float* __restrict__ W1, const float* __restrict__ b1,
    const float* __restrict__ W2, const float* __restrict__ b2,
    float* __restrict__ out, int nE) {
  int e = blockIdx.x * 256 + threadIdx.x;
  if (e >= nE) return;
  int s = ei[e];
  int d = ei[e + nE];
  const float4* mu4 = (const float4*)(x + (size_t)s * D);
  const float4* mv4 = (const float4*)(x + (size_t)d * D);
  float mu[D], mv[D], c[D], p[D];
#pragma unroll
  for (int qq = 0; qq < D / 4; ++qq) {
    float4 a = mu4[qq];
    float4 b = mv4[qq];
    mu[4*qq+0] = a.x; mv[4*qq+0] = b.x; c[4*qq+0] = fabsf(a.x-b.x); p[4*qq+0] = a.x*b.x;
    mu[4*qq+1] = a.y; mv[4*qq+1] = b.y; c[4*qq+1] = fabsf(a.y-b.y); p[4*qq+1] = a.y*b.y;
    mu[4*qq+2] = a.z; mv[4*qq+2] = b.z; c[4*qq+2] = fabsf(a.z-b.z); p[4*qq+2] = a.z*b.z;
    mu[4*qq+3] = a.w; mv[4*qq+3] = b.w; c[4*qq+3] = fabsf(a.w-b.w); p[4*qq+3] = a.w*b.w;
  }
  float z = b2[0];
  for (int j = 0; j < H; ++j) {
    float a = b1[j];
#pragma unroll
    for (int k = 0; k < D; ++k) {
      a = fmaf(mu[k], W1[k * H + j], a);
      a = fmaf(mv[k], W1[(D + k) * H + j], a);
      a = fmaf(c[k],  W1[(2 * D + k) * H + j], a);
      a = fmaf(p[k],  W1[(3 * D + k) * H + j], a);
    }
    a = fmaxf(a, 0.f);
    z = fmaf(a, W2[j], z);
  }
  float g = 1.f / (1.f + __expf(-z));
  out[e] = fminf(fmaxf(g, 0.f), 1.f);
}

extern "C" void kernel_launch(void* const* d_in, const int* in_sizes, int n_in,
                              void* d_out, int out_size, void* d_ws, size_t ws_size,
                              hipStream_t stream) {
  const float* x  = (const float*)d_in[0];
  const int*   ei = (const int*)d_in[1];
  const float* W1 = (const float*)d_in[2];
  const float* b1 = (const float*)d_in[3];
  const float* W2 = (const float*)d_in[4];
  const float* b2 = (const float*)d_in[5];
  float* out = (float*)d_out;

  int nN = in_sizes[0] / D;      // 100000
  int nE = in_sizes[1] / 2;      // 1600000

  size_t xbf_shorts = (size_t)nN * D;                     // 6.4 MB
  size_t need = (xbf_shorts + 16 * 64 * 8) * sizeof(short);
  if (ws_size >= need) {
    short* xbf  = (short*)d_ws;
    short* btab = xbf + xbf_shorts;
    int n4 = nN * D / 4;
    int nPack = (n4 + 255) / 256;
    int nBt = (16 * 64 * 8 + 255) / 256;
    prep<<<nPack + nBt, 256, 0, stream>>>(x, W1, xbf, btab, n4, nPack);
    int nTiles = (nE + 15) / 16;
    int nPairs = (nTiles + 1) / 2;
    edge_mfma<<<2048, 256, 0, stream>>>(xbf, btab, ei, b1, W2, b2, out, nE, nPairs);
  } else {
    edge_full<<<(nE + 255) / 256, 256, 0, stream>>>(x, ei, W1, b1, W2, b2, out, nE);
  }
}